// Round 5
// baseline (204.242 us; speedup 1.0000x reference)
//
#include <hip/hip_runtime.h>

#define BB 8
#define CC 128
#define HH 128
#define WW 128
#define PP 32768
#define HWW (HH * WW)
#define CCB (CC * 2)   // bf16 row bytes

typedef float v4f __attribute__((ext_vector_type(4)));
typedef int   v4i __attribute__((ext_vector_type(4)));
typedef unsigned short v8u __attribute__((ext_vector_type(8)));

__device__ inline unsigned short cvt_bf16_rne(float f) {
    unsigned int u = __float_as_uint(f);
    unsigned int r = (u + 0x7fffu + ((u >> 16) & 1u)) >> 16;
    return (unsigned short)r;
}

// ---------------------------------------------------------------------------
// Kernel 1: transpose feat_grid NCHW fp32 -> NHWC bf16 (RNE).
// 64-spatial x 128-channel tile per block. Read: v4f/lane (16 B, coalesced
// along W). Write: ushort8/lane (16 B, 256 B contiguous per spatial row =
// one full NHWC row per 16 lanes). LDS fp32 tile, +4 pad.
// ---------------------------------------------------------------------------
__global__ __launch_bounds__(256) void transpose_bf16_kernel(
    const float* __restrict__ in,        // [B, C, HW] fp32
    unsigned short* __restrict__ out)    // [B, HW, C] bf16
{
    __shared__ float tile[64][132];      // 33 KiB
    const int b = blockIdx.y;
    const int sBase = blockIdx.x * 64;
    const int tid = threadIdx.x;

    const float* inb = in + (size_t)b * CC * HWW;
    unsigned short* outb = out + (size_t)b * HWW * CC;

    // ---- read: tx = spatial float4 (0..15), c0 = channel (0..15, x8) ----
    const int tx = tid & 15;
    const int c0 = tid >> 4;
#pragma unroll
    for (int i = 0; i < 8; ++i) {
        const int c = c0 + 16 * i;
        const v4f v = *(const v4f*)(inb + (size_t)c * HWW + sBase + 4 * tx);
#pragma unroll
        for (int j = 0; j < 4; ++j)
            tile[4 * tx + j][c] = v[j];
    }
    __syncthreads();

    // ---- write: cx = 8-channel group (0..15), s0 = spatial (0..15, x4) ----
    const int cx = tid & 15;
    const int s0 = tid >> 4;
#pragma unroll
    for (int i = 0; i < 4; ++i) {
        const int s = s0 + 16 * i;
        const float* src = &tile[s][8 * cx];      // 32 B contiguous: 2x b128
        v8u h;
#pragma unroll
        for (int j = 0; j < 8; ++j) h[j] = cvt_bf16_rne(src[j]);
        *(v8u*)(outb + (size_t)(sBase + s) * CC + 8 * cx) = h;  // 16 B store
    }
}

// ---------------------------------------------------------------------------
// Corner/weight math (reference semantics): in_bounds on raw x,y; corners
// (f,f),(f,c),(c,f),(c,c); int trunc-remainder (C '%', == jnp.fmod on int32)
// then max(,0); dinv = 1/(sqrt(d2)+1e-10); OOB -> 0; denom==0 -> 1; normalize.
// rcp (~1e-7 rel err) is fine against the 8.6e-2 threshold.
// ---------------------------------------------------------------------------
__device__ inline void compute_corners(float x, float y,
                                       int gx[4], int gy[4], float wgt[4])
{
    const bool inb = (x >= 0.f) && (y >= 0.f) &&
                     (x <= (float)(WW - 1)) && (y <= (float)(HH - 1));
    const float fx = floorf(x), cx = ceilf(x);
    const float fy = floorf(y), cy = ceilf(y);
    const float corx[4] = {fx, fx, cx, cx};
    const float cory[4] = {fy, cy, fy, cy};
    float denom = 0.f;
#pragma unroll
    for (int k = 0; k < 4; ++k) {
        int gxi = ((int)corx[k]) % WW;
        int gyi = ((int)cory[k]) % HH;
        if (gxi < 0) gxi = 0;
        if (gyi < 0) gyi = 0;
        const float dx = x - (float)gxi;
        const float dy = y - (float)gyi;
        const float dinv = __builtin_amdgcn_rcpf(sqrtf(dx * dx + dy * dy) + 1e-10f);
        const float w = inb ? dinv : 0.f;
        gx[k] = gxi;
        gy[k] = gyi;
        wgt[k] = w;
        denom += w;
    }
    const float rden = (denom == 0.f) ? 1.f : __builtin_amdgcn_rcpf(denom);
#pragma unroll
    for (int k = 0; k < 4; ++k) wgt[k] *= rden;
}

// ---------------------------------------------------------------------------
// Kernel 2: per-point weight/index precompute. 1 thread = 1 point.
// Indices stored as BYTE offsets into the bf16 NHWC grid (kills a shift in
// the gather hot loop). 16 B coalesced stores.
// ---------------------------------------------------------------------------
__global__ __launch_bounds__(256) void weights_kernel(
    const float* __restrict__ tk,        // [B*P, 2]
    v4i* __restrict__ idx_out,           // [B*P] byte offsets
    v4f* __restrict__ wgt_out)           // [B*P]
{
    const int p = blockIdx.x * 256 + (int)threadIdx.x;   // exact grid
    const float2 xy = ((const float2*)tk)[p];            // STRIDE==1: no div

    int gx[4], gy[4];
    float wgt[4];
    compute_corners(xy.x, xy.y, gx, gy, wgt);

    v4i id;
    id[0] = (gy[0] * WW + gx[0]) << 8;   // * CCB
    id[1] = (gy[1] * WW + gx[1]) << 8;
    id[2] = (gy[2] * WW + gx[2]) << 8;
    id[3] = (gy[3] * WW + gx[3]) << 8;
    idx_out[p] = id;
    v4f w = {wgt[0], wgt[1], wgt[2], wgt[3]};
    wgt_out[p] = w;
}

// ---------------------------------------------------------------------------
// Kernel 3: pure gather from bf16 NHWC workspace. 2 points/wave, half-wave
// (32 lanes) per point, lane owns 4 channels (uint2 = 8 B bf16x4 per corner,
// 256 B contiguous per corner per half-wave). XCD swizzle: blockIdx.x & 7
// pins each batch's 4 MiB bf16 slice to one XCD's L2. idx/wgt loaded
// nontemporally (streamed once; don't evict the grid).
// ---------------------------------------------------------------------------
__global__ __launch_bounds__(256) void gather_bf16_kernel(
    const unsigned short* __restrict__ grid,  // [B, HW, C] bf16
    const v4i* __restrict__ idxs,             // [B*P] byte offsets
    const v4f* __restrict__ wgts,             // [B*P]
    float* __restrict__ out)                  // [B, P, C] fp32
{
    const int blk = blockIdx.x;               // 0..32767
    const int b = blk & 7;                    // XCD-aligned batch
    const int inner = blk >> 3;               // 0..4095
    const int wave = (int)threadIdx.x >> 6;   // 0..3
    const int half = ((int)threadIdx.x >> 5) & 1;
    const int sub = (int)threadIdx.x & 31;

    const int p = b * PP + inner * 8 + wave * 2 + half;

    const v4i id = __builtin_nontemporal_load(&idxs[p]);
    const v4f w = __builtin_nontemporal_load(&wgts[p]);

    const char* gb = (const char*)grid + (size_t)b * HWW * CCB + 8 * sub;

    v4f acc = {0.f, 0.f, 0.f, 0.f};
#pragma unroll
    for (int k = 0; k < 4; ++k) {
        const uint2 u = *(const uint2*)(gb + id[k]);
        v4f v;
        v[0] = __uint_as_float(u.x << 16);
        v[1] = __uint_as_float(u.x & 0xffff0000u);
        v[2] = __uint_as_float(u.y << 16);
        v[3] = __uint_as_float(u.y & 0xffff0000u);
        acc += w[k] * v;
    }
    __builtin_nontemporal_store(acc, (v4f*)out + (size_t)p * (CC / 4) + sub);
}

// ---------------------------------------------------------------------------
// Fallback (ws too small): gather straight from NCHW fp32. Correct, slow.
// ---------------------------------------------------------------------------
__global__ __launch_bounds__(256) void gather_nchw_kernel(
    const float* __restrict__ tk,
    const float* __restrict__ grid,      // [B, C, H, W]
    float* __restrict__ out)
{
    const int wave = (int)((blockIdx.x * blockDim.x + threadIdx.x) >> 6);
    const int lane = threadIdx.x & 63;
    if (wave >= BB * PP) return;
    const int b = wave >> 15;

    const float2 xy = ((const float2*)tk)[wave];
    int gx[4], gy[4];
    float wgt[4];
    compute_corners(xy.x, xy.y, gx, gy, wgt);

    const float* gb = grid + (size_t)b * CC * HWW;
    const int c0 = lane * 2;
    float a0 = 0.f, a1 = 0.f;
#pragma unroll
    for (int k = 0; k < 4; ++k) {
        const int sidx = gy[k] * WW + gx[k];
        a0 += wgt[k] * gb[(size_t)c0 * HWW + sidx];
        a1 += wgt[k] * gb[(size_t)(c0 + 1) * HWW + sidx];
    }
    ((float2*)out)[(size_t)wave * (CC / 2) + lane] = make_float2(a0, a1);
}

extern "C" void kernel_launch(void* const* d_in, const int* in_sizes, int n_in,
                              void* d_out, int out_size, void* d_ws, size_t ws_size,
                              hipStream_t stream) {
    const float* tk = (const float*)d_in[0];   // tk_codes [B,P,2] fp32
    const float* fg = (const float*)d_in[1];   // feat_grid [B,C,H,W] fp32
    float* out = (float*)d_out;                // [B,P,C] fp32

    const size_t gridBytes = (size_t)BB * HWW * CCB;           // 32 MiB bf16
    const size_t idxBytes  = (size_t)BB * PP * sizeof(v4i);    // 4 MiB
    const size_t wgtBytes  = (size_t)BB * PP * sizeof(v4f);    // 4 MiB
    const size_t need = gridBytes + idxBytes + wgtBytes;

    if (ws_size >= need) {
        unsigned short* gbf = (unsigned short*)d_ws;
        v4i* idxs = (v4i*)((char*)d_ws + gridBytes);
        v4f* wgts = (v4f*)((char*)d_ws + gridBytes + idxBytes);

        dim3 tg(HWW / 64, BB);                                    // (256, 8)
        transpose_bf16_kernel<<<tg, 256, 0, stream>>>(fg, gbf);
        weights_kernel<<<(BB * PP) / 256, 256, 0, stream>>>(tk, idxs, wgts);
        gather_bf16_kernel<<<(BB * PP) / 8, 256, 0, stream>>>(gbf, idxs, wgts, out);
    } else {
        const int blocks = (BB * PP * 64) / 256;
        gather_nchw_kernel<<<blocks, 256, 0, stream>>>(tk, fg, out);
    }
}